// Round 11
// baseline (310.138 us; speedup 1.0000x reference)
//
#include <hip/hip_runtime.h>

// Problem dims (fixed by setup_inputs)
#define BATCH 4
#define HH 128
#define WW 128
#define CC 128
#define BIN 64
#define NPIX (BATCH * HH * WW)   // 65536

typedef short bf16x8 __attribute__((ext_vector_type(8)));
typedef float f32x4 __attribute__((ext_vector_type(4)));

// round-to-nearest-even bf16 bits of f
__device__ __forceinline__ unsigned bf_hi(float f) {
    unsigned u = __float_as_uint(f);
    return (u + 0x7fffu + ((u >> 16) & 1u)) >> 16;
}
// A-operand split: per c, k' slots [4c..4c+3] = [xh, xh, xl, xl]
__device__ __forceinline__ uint2 split_aa(float f) {
    unsigned hb = bf_hi(f);
    float lo = f - __uint_as_float(hb << 16);
    unsigned lb = bf_hi(lo);
    return make_uint2(hb | (hb << 16), lb | (lb << 16));
}
// B-operand split: per c, k' slots = [wh, wl, wh, wl] -> same uint twice
__device__ __forceinline__ unsigned split_b(float f) {
    unsigned hb = bf_hi(f);
    float lo = f - __uint_as_float(hb << 16);
    unsigned lb = bf_hi(lo);
    return hb | (lb << 16);
}

// ---------------------------------------------------------------------------
// Kernel 0: W pre-split. W_main/W_ref (128x128 fp32) -> split-bf16 BT LDS
// images: per matrix 8 chunks x [128 d][72 shorts] (64 k' + 8 zero pad),
// exactly the BT layout conv reads. 288KB, written into d_out scratch
// (conv consumes it before attn overwrites d_out).
// ---------------------------------------------------------------------------
__global__ __launch_bounds__(256)
void wsplit_kernel(const float* __restrict__ Wm, const float* __restrict__ Wr,
                   unsigned short* __restrict__ img) {
    const int row = blockIdx.x * 256 + threadIdx.x;   // 0..2047
    const int m = row >> 10;                          // matrix
    const int rr = row & 1023;
    const int chunk = rr >> 7, d = rr & 127;
    const float* W = m ? Wr : Wm;
    unsigned short* rp = img + ((size_t)(m * 8 + chunk) * 128 + d) * 72;
#pragma unroll
    for (int cg = 0; cg < 4; ++cg) {
        const int c = chunk * 16 + cg * 4;
        unsigned b0 = split_b(W[(size_t)(c + 0) * CC + d]);
        unsigned b1 = split_b(W[(size_t)(c + 1) * CC + d]);
        unsigned b2 = split_b(W[(size_t)(c + 2) * CC + d]);
        unsigned b3 = split_b(W[(size_t)(c + 3) * CC + d]);
        *(uint4*)(rp + cg * 16)     = make_uint4(b0, b0, b1, b1);
        *(uint4*)(rp + cg * 16 + 8) = make_uint4(b2, b2, b3, b3);
    }
    *(uint4*)(rp + 64) = make_uint4(0, 0, 0, 0);      // pad
}

// ---------------------------------------------------------------------------
// Kernel 1: 1x1 conv == GEMM via split-bf16 MFMA.
// B-tile from the pre-split W image via 18x global_load_lds (L2-hot,
// hidden under A-staging). A-staging depth-1 register prefetch,
// straight-line (no address-taken arrays). LDS 36.8KB -> 4 blocks/CU.
// ---------------------------------------------------------------------------
#define AROW 72   // shorts per LDS row (64 k' + 8 pad)

__global__ __launch_bounds__(256, 4)
void conv_mfma_kernel(const float* __restrict__ Xm, const float* __restrict__ Xr,
                      const unsigned short* __restrict__ Wimg,
                      float* __restrict__ Ym, float* __restrict__ Yr) {
    const int mat = blockIdx.y;
    const float* __restrict__ X = mat ? Xr : Xm;
    float* __restrict__ Y       = mat ? Yr : Ym;

    __shared__ unsigned short AT[128 * AROW];   // [px][k'] 18 KB
    __shared__ unsigned short BT[128 * AROW];   // [d][k']  18 KB

    const int t  = threadIdx.x;
    const int wv = t >> 6;
    const int l  = t & 63;
    const int wm = (wv >> 1) * 64;   // wave's px-quadrant
    const int wn = (wv & 1) * 64;    // wave's d-quadrant
    const int lr = l & 15;
    const int lq = l >> 4;
    const int p_base = blockIdx.x * 128;

    const int px = t >> 1, ahalf = t & 1;   // A staging: 2 thr/px, 8 c each

    f32x4 acc[4][4] = {};

    const float* xbase = X + (size_t)(p_base + px) * CC + ahalf * 8;

    // ---- prologue: prefetch X chunk 0 into registers ----
    float4 xa0 = *(const float4*)(xbase);
    float4 xa1 = *(const float4*)(xbase + 4);

    for (int kc16 = 0; kc16 < 8; ++kc16) {   // 8 chunks of 16 c (64 k')
        __syncthreads();                     // prev MFMA done; X prefetch drained
        // ---- issue W-image DMA for this chunk (drained at next barrier) ----
        {
            const unsigned short* imgrow = Wimg + (size_t)(mat * 8 + kc16) * 9216;
            for (int i = wv; i < 18; i += 4) {
                __builtin_amdgcn_global_load_lds(
                    (const __attribute__((address_space(1))) void*)(imgrow + i * 512 + l * 8),
                    (__attribute__((address_space(3))) void*)&BT[i * 512],
                    16, 0, 0);
            }
        }
        // ---- stage A from regs (fp32 -> [h,h,l,l] bf16) ----
        {
            unsigned short* arow = &AT[px * AROW + ahalf * 32];
            {
                uint2 a0 = split_aa(xa0.x), a1 = split_aa(xa0.y),
                      a2 = split_aa(xa0.z), a3 = split_aa(xa0.w);
                *(uint4*)(arow)     = make_uint4(a0.x, a0.y, a1.x, a1.y);
                *(uint4*)(arow + 8) = make_uint4(a2.x, a2.y, a3.x, a3.y);
            }
            {
                uint2 a0 = split_aa(xa1.x), a1 = split_aa(xa1.y),
                      a2 = split_aa(xa1.z), a3 = split_aa(xa1.w);
                *(uint4*)(arow + 16) = make_uint4(a0.x, a0.y, a1.x, a1.y);
                *(uint4*)(arow + 24) = make_uint4(a2.x, a2.y, a3.x, a3.y);
            }
        }
        __syncthreads();                     // drains W DMA + A ds_writes
        // ---- prefetch X chunk kc16+1 (overlaps MFMA below) ----
        if (kc16 < 7) {
            const float* xp = xbase + kc16 * 16 + 16;
            xa0 = *(const float4*)(xp);
            xa1 = *(const float4*)(xp + 4);
        }
        // ---- MFMA: 2 k-steps of 32 ----
#pragma unroll
        for (int ks = 0; ks < 2; ++ks) {
            bf16x8 af[4], bfr[4];
#pragma unroll
            for (int mi = 0; mi < 4; ++mi)
                af[mi] = *(const bf16x8*)&AT[(wm + mi * 16 + lr) * AROW + ks * 32 + lq * 8];
#pragma unroll
            for (int ni = 0; ni < 4; ++ni)
                bfr[ni] = *(const bf16x8*)&BT[(wn + ni * 16 + lr) * AROW + ks * 32 + lq * 8];
#pragma unroll
            for (int mi = 0; mi < 4; ++mi)
#pragma unroll
                for (int ni = 0; ni < 4; ++ni)
                    acc[mi][ni] = __builtin_amdgcn_mfma_f32_16x16x32_bf16(
                        af[mi], bfr[ni], acc[mi][ni], 0, 0, 0);
        }
    }

    // epilogue: C/D layout col=lane&15, row=(lane>>4)*4+reg
#pragma unroll
    for (int mi = 0; mi < 4; ++mi)
#pragma unroll
        for (int ni = 0; ni < 4; ++ni)
#pragma unroll
            for (int reg = 0; reg < 4; ++reg) {
                const int row = p_base + wm + mi * 16 + lq * 4 + reg;
                Y[(size_t)row * CC + wn + ni * 16 + lr] = acc[mi][ni][reg];
            }
}

// ---------------------------------------------------------------------------
// Kernel 2: local 5x5 attention.
// v10 over v9 (counter-driven):
//  - GSLOT 257->253: LDS 64,768B < 64KB. v9's 66,048B may round past 64KB
//    in the allocator -> 1 block/CU (Occupancy 19% matched 1-block, not 2).
//    253 odd keeps bank skew (part bases {0,20,8,28,16,4,24,12}).
//    Last staging chunk exec-masked (ln<61) so group g never overwrites
//    group g+1's first slots.
//  - Merged-butterfly softmax: fold both pixels' 8-part reductions into
//    one array via select+shfl (75 shfl), softmax ONCE per lane (own px,
//    even parts=px0, odd=px1; 25 exp not 50), then one shfl level (25) to
//    redistribute weights. shfl 150->100/thread, softmax exec halved.
//  - Value mix: interior columns (du=1..4) accumulate BOTH pixels off one
//    shared V read as adjacent fmaf pairs (v_pk_fma_f32-friendly).
// Structure: 64 pixel-PAIRS x 8 channel-parts, (512,2) -> 128-VGPR budget
// (v9 measured 108, no spill). Pair windows union-read 5x6=30 vectors.
// OOB: staged addrs clamped; logits of invalid neighbors = 0; their
// softmax weights = 0 (exact zero-pad semantics).
// ---------------------------------------------------------------------------
#define TH 8
#define TW 16
#define HROW 21        // padded halo row width in float4 (20 real + 1 pad)
#define GSLOT 253      // 12*21=252 real slots + 1 (odd => bank skew); <64KB total
#define NSLOT (8 * GSLOT)   // 2024 slots per buffer

__global__ __launch_bounds__(512, 2)
void attn_tile_kernel(const float* __restrict__ qm, const float* __restrict__ kr,
                      const float* __restrict__ vv, float* __restrict__ out) {
    __shared__ float4 KS[2][NSLOT];   // 64,768 B

    const int t    = threadIdx.x;
    const int wid  = t >> 6;          // wave 0..7 == staging group
    const int ln   = t & 63;
    const int part = t & 7;           // channel-eighth owned by this lane
    const int pxi  = t >> 3;          // pixel-PAIR 0..63 within tile

    const int bi = blockIdx.x >> 7;           // batch
    const int ty = (blockIdx.x >> 3) & 15;    // 16 tile-rows of 8
    const int tx = blockIdx.x & 7;            // 8 tile-cols of 16
    const int h0 = ty * TH, w0 = tx * TW;
    const int r  = pxi >> 3;                  // row 0..7
    const int c2 = (pxi & 7) * 2;             // left col of pair: 0,2,..,14
    const int h = h0 + r, w = w0 + c2;
    const int gbase = bi * HH * WW;
    const int pix0 = gbase + h * WW + w;      // left pixel
    const int pix1 = pix0 + 1;                // right pixel (w+1 <= 127)

    // 25-bit validity masks for the two pixels' windows
    unsigned vm0 = 0, vm1 = 0;
#pragma unroll
    for (int dy = 0; dy < 5; ++dy)
#pragma unroll
        for (int dx = 0; dx < 5; ++dx) {
            const int hh = h + dy - 2;
            const int ww0 = w + dx - 2, ww1 = w + 1 + dx - 2;
            if ((unsigned)hh < (unsigned)HH && (unsigned)ww0 < (unsigned)WW)
                vm0 |= 1u << (dy * 5 + dx);
            if ((unsigned)hh < (unsigned)HH && (unsigned)ww1 < (unsigned)WW)
                vm1 |= 1u << (dy * 5 + dx);
        }

    // hoisted staging pixel indices (wave wid stages group wid; chunks of
    // 64 slots; last chunk masked to 61 lanes). Named scalars, not an
    // array (round-5 lesson: address-taken arrays spill).
    int spx0, spx1, spx2, spx3;
    {
#pragma unroll
        for (int i = 0; i < 4; ++i) {
            const int slot = i * 64 + ln;
            const int py  = slot / 21;
            const int pxx = slot - py * 21;
            int hh = h0 + py - 2;  hh = hh < 0 ? 0 : (hh > HH - 1 ? HH - 1 : hh);
            int ww = w0 + pxx - 2; ww = ww < 0 ? 0 : (ww > WW - 1 ? WW - 1 : ww);
            const int pv = gbase + hh * WW + ww;
            if (i == 0) spx0 = pv; else if (i == 1) spx1 = pv;
            else if (i == 2) spx2 = pv; else spx3 = pv;
        }
    }

    auto stage = [&](int p, int buf) {
        const float* src = (p < 4) ? kr : vv;
        const int ld = (p < 4) ? CC : BIN;
        const int ch = ((p < 4) ? p * 32 : (p - 4) * 32) + wid * 4;
        __builtin_amdgcn_global_load_lds(
            (const __attribute__((address_space(1))) void*)(src + (size_t)spx0 * ld + ch),
            (__attribute__((address_space(3))) void*)&KS[buf][wid * GSLOT], 16, 0, 0);
        __builtin_amdgcn_global_load_lds(
            (const __attribute__((address_space(1))) void*)(src + (size_t)spx1 * ld + ch),
            (__attribute__((address_space(3))) void*)&KS[buf][wid * GSLOT + 64], 16, 0, 0);
        __builtin_amdgcn_global_load_lds(
            (const __attribute__((address_space(1))) void*)(src + (size_t)spx2 * ld + ch),
            (__attribute__((address_space(3))) void*)&KS[buf][wid * GSLOT + 128], 16, 0, 0);
        if (ln < GSLOT - 192)   // 61 lanes: slots 192..252
            __builtin_amdgcn_global_load_lds(
                (const __attribute__((address_space(1))) void*)(src + (size_t)spx3 * ld + ch),
                (__attribute__((address_space(3))) void*)&KS[buf][wid * GSLOT + 192], 16, 0, 0);
    };

    float lg0[25], lg1[25];
#pragma unroll
    for (int i = 0; i < 25; ++i) { lg0[i] = 0.0f; lg1[i] = 0.0f; }

    stage(0, 0);
    __syncthreads();

    for (int p = 0; p < 6; ++p) {
        if (p < 5) stage(p + 1, (p + 1) & 1);   // prefetch into other buffer
        const float4* Bp = KS[p & 1] + part * GSLOT;
        if (p < 4) {
            // ---- logits chunk: 32 channels, this lane's 4, both pixels ----
            const float4 q0 = *(const float4*)(qm + (size_t)pix0 * CC + p * 32 + part * 4);
            const float4 q1 = *(const float4*)(qm + (size_t)pix1 * CC + p * 32 + part * 4);
            // union of the two 5x5 windows: 5 rows x 6 cols
#pragma unroll
            for (int dy = 0; dy < 5; ++dy)
#pragma unroll
                for (int du = 0; du < 6; ++du) {
                    const int hp = (r + dy) * HROW + (c2 + du);
                    const float4 k = Bp[hp];
                    if (du < 5)
                        lg0[dy * 5 + du] += q0.x * k.x + q0.y * k.y +
                                            q0.z * k.z + q0.w * k.w;
                    if (du > 0)
                        lg1[dy * 5 + du - 1] += q1.x * k.x + q1.y * k.y +
                                                q1.z * k.z + q1.w * k.w;
                }
        } else {
            if (p == 4) {
                const bool odd = (part & 1);
                // merged butterfly: even parts reduce lg0 (px0), odd lg1
                // (px1) — one array instead of two (75 shfl vs 150).
#pragma unroll
                for (int kk = 0; kk < 25; ++kk) {
                    const float send = odd ? lg0[kk] : lg1[kk];
                    const float keep = odd ? lg1[kk] : lg0[kk];
                    float a = keep + __shfl_xor(send, 1);
                    a += __shfl_xor(a, 2);
                    a += __shfl_xor(a, 4);
                    lg0[kk] = a;          // own-pixel combined logits
                }
                // softmax ONCE per lane on own pixel
                const unsigned vme = odd ? vm1 : vm0;
#pragma unroll
                for (int kk = 0; kk < 25; ++kk)
                    if (!((vme >> kk) & 1)) lg0[kk] = 0.0f;
                float mx = lg0[0];
#pragma unroll
                for (int kk = 1; kk < 25; ++kk) mx = fmaxf(mx, lg0[kk]);
                float sum = 0.0f;
#pragma unroll
                for (int kk = 0; kk < 25; ++kk) {
                    lg0[kk] = __expf(lg0[kk] - mx);
                    sum += lg0[kk];
                }
                const float inv = 1.0f / sum;
#pragma unroll
                for (int kk = 0; kk < 25; ++kk)
                    lg0[kk] = ((vme >> kk) & 1) ? lg0[kk] * inv : 0.0f;
                // redistribute: lg0 = px0 weights, lg1 = px1 weights
#pragma unroll
                for (int kk = 0; kk < 25; ++kk) {
                    const float o = __shfl_xor(lg0[kk], 1);
                    const float w0 = odd ? o : lg0[kk];
                    const float w1 = odd ? lg0[kk] : o;
                    lg0[kk] = w0;
                    lg1[kk] = w1;
                }
            }
            // ---- value-mix chunk: 32 bins, this lane's 4, both pixels ----
            // pb*.x accumulates px0, pb*.y px1; interior columns share one
            // V read with adjacent fmaf pairs (packs to v_pk_fma_f32).
            float2 pb0 = {0.f, 0.f}, pb1 = {0.f, 0.f},
                   pb2 = {0.f, 0.f}, pb3 = {0.f, 0.f};
#pragma unroll
            for (int dy = 0; dy < 5; ++dy) {
                const int hpb = (r + dy) * HROW + c2;
                {   // du = 0: px0 only
                    const float4 v = Bp[hpb];
                    const float wg = lg0[dy * 5];
                    pb0.x = fmaf(wg, v.x, pb0.x); pb1.x = fmaf(wg, v.y, pb1.x);
                    pb2.x = fmaf(wg, v.z, pb2.x); pb3.x = fmaf(wg, v.w, pb3.x);
                }
#pragma unroll
                for (int du = 1; du < 5; ++du) {
                    const float4 v = Bp[hpb + du];
                    const float w0 = lg0[dy * 5 + du];
                    const float w1 = lg1[dy * 5 + du - 1];
                    pb0.x = fmaf(w0, v.x, pb0.x); pb0.y = fmaf(w1, v.x, pb0.y);
                    pb1.x = fmaf(w0, v.y, pb1.x); pb1.y = fmaf(w1, v.y, pb1.y);
                    pb2.x = fmaf(w0, v.z, pb2.x); pb2.y = fmaf(w1, v.z, pb2.y);
                    pb3.x = fmaf(w0, v.w, pb3.x); pb3.y = fmaf(w1, v.w, pb3.y);
                }
                {   // du = 5: px1 only
                    const float4 v = Bp[hpb + 5];
                    const float wg = lg1[dy * 5 + 4];
                    pb0.y = fmaf(wg, v.x, pb0.y); pb1.y = fmaf(wg, v.y, pb1.y);
                    pb2.y = fmaf(wg, v.z, pb2.y); pb3.y = fmaf(wg, v.w, pb3.y);
                }
            }
            *(float4*)(out + (size_t)pix0 * BIN + (p - 4) * 32 + part * 4) =
                make_float4(pb0.x, pb1.x, pb2.x, pb3.x);
            *(float4*)(out + (size_t)pix1 * BIN + (p - 4) * 32 + part * 4) =
                make_float4(pb0.y, pb1.y, pb2.y, pb3.y);
        }
        __syncthreads();
    }
}

extern "C" void kernel_launch(void* const* d_in, const int* in_sizes, int n_in,
                              void* d_out, int out_size, void* d_ws, size_t ws_size,
                              hipStream_t stream) {
    const float* main_in   = (const float*)d_in[0];
    const float* ref_in    = (const float*)d_in[1];
    const float* ref_value = (const float*)d_in[2];
    const float* W_main    = (const float*)d_in[3];
    const float* W_ref     = (const float*)d_in[4];
    float* out = (float*)d_out;

    float* conv_main = (float*)d_ws;                         // 32 MB
    float* conv_ref  = conv_main + (size_t)NPIX * CC;        // 32 MB

    // W pre-split image (288KB) in d_out scratch: wsplit writes it, conv
    // reads it, attn overwrites d_out afterwards (stream-ordered).
    unsigned short* Wimg = (unsigned short*)d_out;
    wsplit_kernel<<<8, 256, 0, stream>>>(W_main, W_ref, Wimg);

    dim3 gconv(NPIX / 128, 2);   // 1024 blocks = 4/CU
    conv_mfma_kernel<<<gconv, 256, 0, stream>>>(main_in, ref_in, Wimg,
                                                conv_main, conv_ref);

    // 512 blocks = 2/CU: one 8x16 tile, 2 adjacent px/thread, 8 parts
    attn_tile_kernel<<<512, 512, 0, stream>>>(conv_main, conv_ref, ref_value, out);
}

// Round 12
// 172.286 us; speedup vs baseline: 1.8001x; 1.8001x over previous
//
#include <hip/hip_runtime.h>

// Problem dims (fixed by setup_inputs)
#define BATCH 4
#define HH 128
#define WW 128
#define CC 128
#define BIN 64
#define NPIX (BATCH * HH * WW)   // 65536

typedef short bf16x8 __attribute__((ext_vector_type(8)));
typedef float f32x4 __attribute__((ext_vector_type(4)));

// round-to-nearest-even bf16 bits of f
__device__ __forceinline__ unsigned bf_hi(float f) {
    unsigned u = __float_as_uint(f);
    return (u + 0x7fffu + ((u >> 16) & 1u)) >> 16;
}
// A-operand split: per c, k' slots [4c..4c+3] = [xh, xh, xl, xl]
__device__ __forceinline__ uint2 split_aa(float f) {
    unsigned hb = bf_hi(f);
    float lo = f - __uint_as_float(hb << 16);
    unsigned lb = bf_hi(lo);
    return make_uint2(hb | (hb << 16), lb | (lb << 16));
}
// B-operand split: per c, k' slots = [wh, wl, wh, wl] -> same uint twice
__device__ __forceinline__ unsigned split_b(float f) {
    unsigned hb = bf_hi(f);
    float lo = f - __uint_as_float(hb << 16);
    unsigned lb = bf_hi(lo);
    return hb | (lb << 16);
}

// ---------------------------------------------------------------------------
// Kernel 1: 1x1 conv == GEMM via split-bf16 MFMA.  (round-3 measured-best:
// depth-1 register prefetch, straight-line staging — no address-taken local
// arrays. Depth-2/lambda variants spilled to scratch; wsplit variant was
// time-neutral. This exact version measured <45.8us, spill-free.)
// Y[p][d] = sum_c X[p][c]*W[c][d], fp32 reproduced as (xh+xl)*(wh+wl),
// K'=512 (4 bf16 slots per c). 128px x 128d tile, K' chunked by 64 (16 c).
// ---------------------------------------------------------------------------
#define AROW 72   // shorts per LDS row (64 k' + 8 pad)

__global__ __launch_bounds__(256, 4)
void conv_mfma_kernel(const float* __restrict__ Xm, const float* __restrict__ Xr,
                      const float* __restrict__ Wm, const float* __restrict__ Wr,
                      float* __restrict__ Ym, float* __restrict__ Yr) {
    const float* __restrict__ X = blockIdx.y ? Xr : Xm;
    const float* __restrict__ W = blockIdx.y ? Wr : Wm;
    float* __restrict__ Y       = blockIdx.y ? Yr : Ym;

    __shared__ unsigned short AT[128 * AROW];   // [px][k'] 18 KB
    __shared__ unsigned short BT[128 * AROW];   // [d][k']  18 KB

    const int t  = threadIdx.x;
    const int wv = t >> 6;
    const int l  = t & 63;
    const int wm = (wv >> 1) * 64;   // wave's px-quadrant
    const int wn = (wv & 1) * 64;    // wave's d-quadrant
    const int lr = l & 15;
    const int lq = l >> 4;
    const int p_base = blockIdx.x * 128;

    const int px = t >> 1, ahalf = t & 1;   // A staging: 2 thr/px, 8 c each
    const int d  = t & 127, bq = t >> 7;    // B staging: 2 thr/d, 8 c each

    f32x4 acc[4][4] = {};

    const float* xbase = X + (size_t)(p_base + px) * CC + ahalf * 8;

    // ---- prologue: prefetch chunk 0 into registers ----
    float4 xa0 = *(const float4*)(xbase);
    float4 xa1 = *(const float4*)(xbase + 4);
    float wb0, wb1, wb2, wb3, wb4, wb5, wb6, wb7;
    {
        const float* wp0 = W + (size_t)(bq * 2 * 4) * CC + d;
        wb0 = wp0[0]; wb1 = wp0[CC]; wb2 = wp0[2 * CC]; wb3 = wp0[3 * CC];
        const float* wp1 = W + (size_t)((bq * 2 + 1) * 4) * CC + d;
        wb4 = wp1[0]; wb5 = wp1[CC]; wb6 = wp1[2 * CC]; wb7 = wp1[3 * CC];
    }

    for (int kc = 0; kc < CC; kc += 16) {   // 16 c per chunk = 64 k'
        __syncthreads();                    // prev MFMA reads done
        // ---- stage A from regs (fp32 -> [h,h,l,l] bf16) ----
        {
            unsigned short* arow = &AT[px * AROW + ahalf * 32];
            {
                uint2 a0 = split_aa(xa0.x), a1 = split_aa(xa0.y),
                      a2 = split_aa(xa0.z), a3 = split_aa(xa0.w);
                *(uint4*)(arow)     = make_uint4(a0.x, a0.y, a1.x, a1.y);
                *(uint4*)(arow + 8) = make_uint4(a2.x, a2.y, a3.x, a3.y);
            }
            {
                uint2 a0 = split_aa(xa1.x), a1 = split_aa(xa1.y),
                      a2 = split_aa(xa1.z), a3 = split_aa(xa1.w);
                *(uint4*)(arow + 16) = make_uint4(a0.x, a0.y, a1.x, a1.y);
                *(uint4*)(arow + 24) = make_uint4(a2.x, a2.y, a3.x, a3.y);
            }
        }
        // ---- stage B from regs (fp32 -> [h,l,h,l] bf16, [d][k']) ----
        {
            unsigned b0 = split_b(wb0), b1 = split_b(wb1),
                     b2 = split_b(wb2), b3 = split_b(wb3);
            unsigned short* brow = &BT[d * AROW + (bq * 2) * 16];
            *(uint4*)(brow)     = make_uint4(b0, b0, b1, b1);
            *(uint4*)(brow + 8) = make_uint4(b2, b2, b3, b3);
            unsigned c0 = split_b(wb4), c1 = split_b(wb5),
                     c2 = split_b(wb6), c3 = split_b(wb7);
            unsigned short* brow2 = &BT[d * AROW + (bq * 2 + 1) * 16];
            *(uint4*)(brow2)     = make_uint4(c0, c0, c1, c1);
            *(uint4*)(brow2 + 8) = make_uint4(c2, c2, c3, c3);
        }
        __syncthreads();
        // ---- prefetch chunk kc+16 (overlaps MFMA below) ----
        if (kc + 16 < CC) {
            const float* xp = xbase + kc + 16;
            xa0 = *(const float4*)(xp);
            xa1 = *(const float4*)(xp + 4);
            const float* wp0 = W + (size_t)(kc + 16 + bq * 2 * 4) * CC + d;
            wb0 = wp0[0]; wb1 = wp0[CC]; wb2 = wp0[2 * CC]; wb3 = wp0[3 * CC];
            const float* wp1 = W + (size_t)(kc + 16 + (bq * 2 + 1) * 4) * CC + d;
            wb4 = wp1[0]; wb5 = wp1[CC]; wb6 = wp1[2 * CC]; wb7 = wp1[3 * CC];
        }
        // ---- MFMA: 2 k-steps of 32 ----
#pragma unroll
        for (int ks = 0; ks < 2; ++ks) {
            bf16x8 af[4], bfr[4];
#pragma unroll
            for (int mi = 0; mi < 4; ++mi)
                af[mi] = *(const bf16x8*)&AT[(wm + mi * 16 + lr) * AROW + ks * 32 + lq * 8];
#pragma unroll
            for (int ni = 0; ni < 4; ++ni)
                bfr[ni] = *(const bf16x8*)&BT[(wn + ni * 16 + lr) * AROW + ks * 32 + lq * 8];
#pragma unroll
            for (int mi = 0; mi < 4; ++mi)
#pragma unroll
                for (int ni = 0; ni < 4; ++ni)
                    acc[mi][ni] = __builtin_amdgcn_mfma_f32_16x16x32_bf16(
                        af[mi], bfr[ni], acc[mi][ni], 0, 0, 0);
        }
    }

    // epilogue: C/D layout col=lane&15, row=(lane>>4)*4+reg
#pragma unroll
    for (int mi = 0; mi < 4; ++mi)
#pragma unroll
        for (int ni = 0; ni < 4; ++ni)
#pragma unroll
            for (int reg = 0; reg < 4; ++reg) {
                const int row = p_base + wm + mi * 16 + lq * 4 + reg;
                Y[(size_t)row * CC + wn + ni * 16 + lr] = acc[mi][ni][reg];
            }
}

// ---------------------------------------------------------------------------
// Kernel 2: local 5x5 attention, LDS-tiled with async prefetch.  (round-3
// measured-best: 46.2us, VGPR 80, spill-free. All later variants — pair-
// pixel at 4 parts/(256,1), 8 parts/(512,2|4), merged-butterfly softmax —
// regressed via VGPR spills or halved occupancy. Reverted.)
//  - __launch_bounds__(512,2): natural ~80 VGPRs, 16 waves/CU, no spill.
//  - GSLOT=257: group stride 4112B = 8-bank skew -> the 4 channel-parts
//    of a pixel land on bank bases {0,8,16,24}; worst 2-way (free).
// Structure: 8x16 tile, 512 thr (4/px), 6 phases (4 K-chunks + 2 V-chunks
// of 32 ch) double-buffered via global_load_lds. LDS 2x2056x16B = 65.8KB
// -> 2 blocks/CU. OOB: staged addrs clamped; logits of invalid neighbors
// = 0; their softmax weights = 0 (exact zero-pad semantics).
// ---------------------------------------------------------------------------
#define TH 8
#define TW 16
#define HROW 21        // padded halo row width in float4 (20 real + 1 pad)
#define GSLOT 257      // slots per channel-group (12*21=252 real + pad), odd*16B bank skew
#define NSLOT (8 * GSLOT)   // 2056 slots per buffer

__global__ __launch_bounds__(512, 2)
void attn_tile_kernel(const float* __restrict__ qm, const float* __restrict__ kr,
                      const float* __restrict__ vv, float* __restrict__ out) {
    __shared__ float4 KS[2][NSLOT];   // 65.8 KB

    const int t    = threadIdx.x;
    const int wid  = t >> 6;
    const int ln   = t & 63;
    const int part = t & 3;           // channel-quarter owned by this lane
    const int pxi  = t >> 2;          // pixel 0..127 within tile

    const int bi = blockIdx.x >> 7;           // batch
    const int ty = (blockIdx.x >> 3) & 15;    // 16 tile-rows of 8
    const int tx = blockIdx.x & 7;            // 8 tile-cols of 16
    const int h0 = ty * TH, w0 = tx * TW;
    const int r = pxi >> 4, c = pxi & 15;
    const int h = h0 + r, w = w0 + c;
    const int gbase = bi * HH * WW;
    const int pix = gbase + h * WW + w;
    const int g0 = part * 2;                  // this lane's float4 groups

    // 25-bit validity mask for this pixel's window
    unsigned vm = 0;
#pragma unroll
    for (int dy = 0; dy < 5; ++dy)
#pragma unroll
        for (int dx = 0; dx < 5; ++dx) {
            const int hh = h + dy - 2, ww = w + dx - 2;
            if ((unsigned)hh < (unsigned)HH && (unsigned)ww < (unsigned)WW)
                vm |= 1u << (dy * 5 + dx);
        }

    // wave wid stages channel-group wid: 4 DMA chunks of 64 slots cover the
    // 252 real halo slots (+4 clamped pads). DMA dest = uniform base + ln*16.
    auto stage = [&](int p, int buf) {
        const float* src = (p < 4) ? kr : vv;
        const int ld = (p < 4) ? CC : BIN;
        const int ch = ((p < 4) ? p * 32 : (p - 4) * 32) + wid * 4;
#pragma unroll
        for (int i = 0; i < 4; ++i) {
            const int px  = i * 64 + ln;        // halo slot 0..255
            const int py  = px / 21;            // 0..12 (12 = pad row)
            const int pxx = px - py * 21;       // 0..20 (20 = pad col)
            int hh = h0 + py - 2;  hh = hh < 0 ? 0 : (hh > HH - 1 ? HH - 1 : hh);
            int ww = w0 + pxx - 2; ww = ww < 0 ? 0 : (ww > WW - 1 ? WW - 1 : ww);
            const float* gp = src + (size_t)(gbase + hh * WW + ww) * ld + ch;
            __builtin_amdgcn_global_load_lds(
                (const __attribute__((address_space(1))) void*)gp,
                (__attribute__((address_space(3))) void*)&KS[buf][wid * GSLOT + i * 64],
                16, 0, 0);
        }
    };

    float lg[25];
#pragma unroll
    for (int i = 0; i < 25; ++i) lg[i] = 0.0f;

    stage(0, 0);
    __syncthreads();

    for (int p = 0; p < 6; ++p) {
        if (p < 5) stage(p + 1, (p + 1) & 1);   // prefetch into other buffer
        const float4* B = KS[p & 1];
        if (p < 4) {
            // ---- logits chunk: 32 channels, this lane's 8 ----
            const float4* qp = (const float4*)(qm + (size_t)pix * CC + p * 32 + part * 8);
            float4 q0 = qp[0], q1 = qp[1];
#pragma unroll
            for (int dy = 0; dy < 5; ++dy)
#pragma unroll
                for (int dx = 0; dx < 5; ++dx) {
                    const int hp = (r + dy) * HROW + (c + dx);
                    float4 k0 = B[g0 * GSLOT + hp];
                    float4 k1 = B[g0 * GSLOT + GSLOT + hp];
                    lg[dy * 5 + dx] += q0.x * k0.x + q0.y * k0.y +
                                       q0.z * k0.z + q0.w * k0.w +
                                       q1.x * k1.x + q1.y * k1.y +
                                       q1.z * k1.z + q1.w * k1.w;
                }
        } else {
            if (p == 4) {
                // combine the 4 channel-quarters' partial logits
#pragma unroll
                for (int kk = 0; kk < 25; ++kk) {
                    float v = lg[kk];
                    v += __shfl_xor(v, 1);
                    v += __shfl_xor(v, 2);
                    lg[kk] = v;
                }
                // mask OOB logits to 0 (exact zero-pad semantics), softmax,
                // then zero the weights of OOB neighbors
#pragma unroll
                for (int kk = 0; kk < 25; ++kk)
                    if (!((vm >> kk) & 1)) lg[kk] = 0.0f;
                float mx = lg[0];
#pragma unroll
                for (int kk = 1; kk < 25; ++kk) mx = fmaxf(mx, lg[kk]);
                float sum = 0.0f;
#pragma unroll
                for (int kk = 0; kk < 25; ++kk) {
                    lg[kk] = __expf(lg[kk] - mx);
                    sum += lg[kk];
                }
                const float inv = 1.0f / sum;
#pragma unroll
                for (int kk = 0; kk < 25; ++kk)
                    lg[kk] = ((vm >> kk) & 1) ? lg[kk] * inv : 0.0f;
            }
            // ---- value-mix chunk: 32 bins, this lane's 8 ----
            float4 a0 = make_float4(0.f, 0.f, 0.f, 0.f);
            float4 a1 = make_float4(0.f, 0.f, 0.f, 0.f);
#pragma unroll
            for (int dy = 0; dy < 5; ++dy)
#pragma unroll
                for (int dx = 0; dx < 5; ++dx) {
                    const float wgt = lg[dy * 5 + dx];
                    const int hp = (r + dy) * HROW + (c + dx);
                    float4 v0 = B[g0 * GSLOT + hp];
                    float4 v1 = B[g0 * GSLOT + GSLOT + hp];
                    a0.x += wgt * v0.x; a0.y += wgt * v0.y;
                    a0.z += wgt * v0.z; a0.w += wgt * v0.w;
                    a1.x += wgt * v1.x; a1.y += wgt * v1.y;
                    a1.z += wgt * v1.z; a1.w += wgt * v1.w;
                }
            float4* op = (float4*)(out + (size_t)pix * BIN + (p - 4) * 32 + part * 8);
            op[0] = a0;
            op[1] = a1;
        }
        __syncthreads();
    }
}

extern "C" void kernel_launch(void* const* d_in, const int* in_sizes, int n_in,
                              void* d_out, int out_size, void* d_ws, size_t ws_size,
                              hipStream_t stream) {
    const float* main_in   = (const float*)d_in[0];
    const float* ref_in    = (const float*)d_in[1];
    const float* ref_value = (const float*)d_in[2];
    const float* W_main    = (const float*)d_in[3];
    const float* W_ref     = (const float*)d_in[4];
    float* out = (float*)d_out;

    float* conv_main = (float*)d_ws;                         // 32 MB
    float* conv_ref  = conv_main + (size_t)NPIX * CC;        // 32 MB

    dim3 gconv(NPIX / 128, 2);   // 1024 blocks = 4/CU
    conv_mfma_kernel<<<gconv, 256, 0, stream>>>(main_in, ref_in, W_main, W_ref,
                                                conv_main, conv_ref);

    // 512 blocks = 2/CU: one 8x16 tile each, 4 threads per pixel
    attn_tile_kernel<<<512, 512, 0, stream>>>(conv_main, conv_ref, ref_value, out);
}